// Round 2
// baseline (502.139 us; speedup 1.0000x reference)
//
#include <hip/hip_runtime.h>
#include <hip/hip_bf16.h>

typedef unsigned short u16;
typedef __attribute__((ext_vector_type(8))) short bf16x8;
typedef __attribute__((ext_vector_type(4))) float f32x4;

#define T_DIM 2048
#define S_DIM 2048
#define B_DIM 2
#define E_DIM 1024
#define H_DIM 16
#define D_HEAD 64
#define NTOK 4096  // T*B

__device__ __forceinline__ float bf2f(u16 u) {
  union { unsigned int i; float f; } v; v.i = ((unsigned int)u) << 16; return v.f;
}
__device__ __forceinline__ u16 f2bf(float f) {
  union { float f; unsigned int i; } v; v.f = f;
  unsigned int r = v.i + 0x7fffu + ((v.i >> 16) & 1u);
  return (u16)(r >> 16);
}

// ---- dtype detector: flag=1 if input buffers are bf16, 0 if f32 -------------
__global__ void detect_dtype(const u16* q, int* flag) {
  int lane = threadIdx.x;  // 64 threads
  float v = bf2f(q[2 * lane]);
  bool ok = (v < 16.f) && (v > -16.f);  // NaN -> false
  unsigned long long b = __ballot(ok);
  if (lane == 0) *flag = (b == ~0ull) ? 1 : 0;
}

__global__ void to_bf16(const void* src, u16* dst, int n, const int* flag) {
  int i = blockIdx.x * blockDim.x + threadIdx.x;
  int stride = gridDim.x * blockDim.x;
  if (*flag) {
    const u16* s = (const u16*)src;
    for (; i < n; i += stride) dst[i] = s[i];
  } else {
    const float* s = (const float*)src;
    for (; i < n; i += stride) dst[i] = f2bf(s[i]);
  }
}

__global__ void to_f32(const void* src, float* dst, int n, const int* flag) {
  int i = blockIdx.x * blockDim.x + threadIdx.x;
  int stride = gridDim.x * blockDim.x;
  if (*flag) {
    const u16* s = (const u16*)src;
    for (; i < n; i += stride) dst[i] = bf2f(s[i]);
  } else {
    const float* s = (const float*)src;
    for (; i < n; i += stride) dst[i] = s[i];
  }
}

// ---- NT GEMM: C[M,N] = (A[M,K] @ B[N,K]^T + bias[N]) * scale ---------------
// 64x64 tile, 4 waves. C/D layout: row=(lane>>4)*4+reg, col=lane&15.
__launch_bounds__(256)
__global__ void gemm_nt(const u16* __restrict__ A, const u16* __restrict__ Bw,
                        const float* __restrict__ bias, void* __restrict__ C,
                        int M, int N, int K, float scale, int out_f32) {
  __shared__ alignas(16) u16 As[64 * 72];
  __shared__ alignas(16) u16 Bs[64 * 72];
  const int tid = threadIdx.x;
  const int wave = tid >> 6, lane = tid & 63;
  const int g = lane >> 4, c = lane & 15;
  const int m0 = blockIdx.y * 64, n0 = blockIdx.x * 64;
  f32x4 acc[4] = {};
  for (int kc = 0; kc < K; kc += 64) {
#pragma unroll
    for (int i = 0; i < 2; i++) {
      int ch = tid + i * 256;  // 512 chunks of 16B
      int r = ch >> 3, o = (ch & 7) * 8;
      *(uint4*)&As[r * 72 + o] = *(const uint4*)&A[(size_t)(m0 + r) * K + kc + o];
      *(uint4*)&Bs[r * 72 + o] = *(const uint4*)&Bw[(size_t)(n0 + r) * K + kc + o];
    }
    __syncthreads();
    const int arow = wave * 16 + c;
#pragma unroll
    for (int ks = 0; ks < 2; ks++) {
      bf16x8 a = *(const bf16x8*)&As[arow * 72 + ks * 32 + g * 8];
#pragma unroll
      for (int n = 0; n < 4; n++) {
        bf16x8 b = *(const bf16x8*)&Bs[(n * 16 + c) * 72 + ks * 32 + g * 8];
        acc[n] = __builtin_amdgcn_mfma_f32_16x16x32_bf16(a, b, acc[n], 0, 0, 0);
      }
    }
    __syncthreads();
  }
#pragma unroll
  for (int n = 0; n < 4; n++)
#pragma unroll
    for (int r = 0; r < 4; r++) {
      int row = m0 + wave * 16 + g * 4 + r;
      int col = n0 + n * 16 + c;
      float v = (acc[n][r] + bias[col]) * scale;
      size_t idx = (size_t)row * N + col;
      if (out_f32) ((float*)C)[idx] = v;
      else         ((u16*)C)[idx] = f2bf(v);
    }
}

// ---- flash attention: 64 Q-rows per block, S-tiles of 64 --------------------
__launch_bounds__(256)
__global__ void flash_attn(const u16* __restrict__ Qb, const u16* __restrict__ Kb,
                           const u16* __restrict__ Vb, const void* __restrict__ mask,
                           const unsigned char* __restrict__ kpm,
                           u16* __restrict__ ctx, const int* __restrict__ flag) {
  __shared__ alignas(16) u16 Qs[64 * 72];
  __shared__ alignas(16) u16 Ks[64 * 72];
  __shared__ alignas(16) u16 Vt[64 * 72];  // transposed: Vt[dcol][s]
  __shared__ alignas(16) u16 Ps[64 * 72];  // P in A-operand layout, wave-private
  const int tid = threadIdx.x;
  const int wave = tid >> 6, lane = tid & 63;
  const int g = lane >> 4, c = lane & 15;
  const int t0 = blockIdx.x * 64;
  const int bh = blockIdx.y;
  const int b = bh / H_DIM, h = bh % H_DIM;
  const size_t hoff = (size_t)h * D_HEAD;
  const int mask_bf = *flag;

#pragma unroll
  for (int i = 0; i < 2; i++) {
    int ch = tid + i * 256;
    int r = ch >> 3, o = (ch & 7) * 8;
    *(uint4*)&Qs[r * 72 + o] =
        *(const uint4*)&Qb[((size_t)(t0 + r) * B_DIM + b) * E_DIM + hoff + o];
  }
  f32x4 O[4] = {};
  float mrow[4] = {-1e30f, -1e30f, -1e30f, -1e30f};
  float lrow[4] = {0.f, 0.f, 0.f, 0.f};
  __syncthreads();

  for (int s0 = 0; s0 < S_DIM; s0 += 64) {
#pragma unroll
    for (int i = 0; i < 2; i++) {
      int ch = tid + i * 256;
      int r = ch >> 3, o = (ch & 7) * 8;
      *(uint4*)&Ks[r * 72 + o] =
          *(const uint4*)&Kb[((size_t)(s0 + r) * B_DIM + b) * E_DIM + hoff + o];
      u16 tmp[8];
      *(uint4*)tmp = *(const uint4*)&Vb[((size_t)(s0 + r) * B_DIM + b) * E_DIM + hoff + o];
#pragma unroll
      for (int j = 0; j < 8; j++) Vt[(o + j) * 72 + r] = tmp[j];
    }
    __syncthreads();

    // scores: this wave's 16 t-rows x 64 s-cols
    f32x4 sc[4] = {};
    {
      const int arow = wave * 16 + c;
#pragma unroll
      for (int ks = 0; ks < 2; ks++) {
        bf16x8 a = *(const bf16x8*)&Qs[arow * 72 + ks * 32 + g * 8];
#pragma unroll
        for (int n = 0; n < 4; n++) {
          bf16x8 kb = *(const bf16x8*)&Ks[(n * 16 + c) * 72 + ks * 32 + g * 8];
          sc[n] = __builtin_amdgcn_mfma_f32_16x16x32_bf16(a, kb, sc[n], 0, 0, 0);
        }
      }
    }
    // additive masks
    float kadd[4];
#pragma unroll
    for (int n = 0; n < 4; n++) {
      int s = s0 + n * 16 + c;
      kadd[n] = kpm[(size_t)b * S_DIM + s] ? -1e9f : 0.f;
    }
#pragma unroll
    for (int n = 0; n < 4; n++) {
      int s = s0 + n * 16 + c;
#pragma unroll
      for (int r = 0; r < 4; r++) {
        int t = t0 + wave * 16 + g * 4 + r;
        size_t midx = (size_t)t * S_DIM + s;
        float mv = mask_bf ? bf2f(((const u16*)mask)[midx]) : ((const float*)mask)[midx];
        sc[n][r] += mv + kadd[n];
      }
    }
    // online softmax (row r of quad g; columns spread over n and lanes c)
    float mnew[4], alpha[4];
#pragma unroll
    for (int r = 0; r < 4; r++) {
      float mx = fmaxf(fmaxf(sc[0][r], sc[1][r]), fmaxf(sc[2][r], sc[3][r]));
#pragma unroll
      for (int off = 1; off < 16; off <<= 1) mx = fmaxf(mx, __shfl_xor(mx, off, 64));
      mnew[r] = fmaxf(mrow[r], mx);
      alpha[r] = __expf(mrow[r] - mnew[r]);
      mrow[r] = mnew[r];
    }
    float p[4][4];
#pragma unroll
    for (int r = 0; r < 4; r++) {
      float s = 0.f;
#pragma unroll
      for (int n = 0; n < 4; n++) { p[n][r] = __expf(sc[n][r] - mnew[r]); s += p[n][r]; }
#pragma unroll
      for (int off = 1; off < 16; off <<= 1) s += __shfl_xor(s, off, 64);
      lrow[r] = lrow[r] * alpha[r] + s;
    }
#pragma unroll
    for (int n = 0; n < 4; n++)
#pragma unroll
      for (int r = 0; r < 4; r++) O[n][r] *= alpha[r];
    // P: C-layout regs -> A-operand row-major LDS (wave-private rows)
#pragma unroll
    for (int n = 0; n < 4; n++)
#pragma unroll
      for (int r = 0; r < 4; r++)
        Ps[(wave * 16 + g * 4 + r) * 72 + n * 16 + c] = f2bf(p[n][r]);
    // O += P @ V
    {
      const int arow = wave * 16 + c;
#pragma unroll
      for (int ks = 0; ks < 2; ks++) {
        bf16x8 a = *(const bf16x8*)&Ps[arow * 72 + ks * 32 + g * 8];
#pragma unroll
        for (int n = 0; n < 4; n++) {
          bf16x8 vb = *(const bf16x8*)&Vt[(n * 16 + c) * 72 + ks * 32 + g * 8];
          O[n] = __builtin_amdgcn_mfma_f32_16x16x32_bf16(a, vb, O[n], 0, 0, 0);
        }
      }
    }
    __syncthreads();
  }
#pragma unroll
  for (int n = 0; n < 4; n++)
#pragma unroll
    for (int r = 0; r < 4; r++) {
      int t = t0 + wave * 16 + g * 4 + r;
      int dcol = n * 16 + c;
      float v = O[n][r] / lrow[r];
      ctx[((size_t)t * B_DIM + b) * E_DIM + hoff + dcol] = f2bf(v);
    }
}

extern "C" void kernel_launch(void* const* d_in, const int* in_sizes, int n_in,
                              void* d_out, int out_size, void* d_ws, size_t ws_size,
                              hipStream_t stream) {
  const void* query = d_in[0];
  const void* key   = d_in[1];
  const void* value = d_in[2];
  const void* amask = d_in[3];
  const unsigned char* kpm = (const unsigned char*)d_in[4];
  const void* Wq = d_in[5];  const void* bq = d_in[6];
  const void* Wk = d_in[7];  const void* bk = d_in[8];
  const void* Wv = d_in[9];  const void* bv = d_in[10];
  const void* Wo = d_in[11]; const void* bo = d_in[12];

  // ---- output dtype decision (host, capture-safe: no stream ops) ----------
  int out_f32 = 0;
  {
    hipDeviceptr_t base = nullptr; size_t sz = 0;
    if (hipMemGetAddressRange(&base, &sz, (hipDeviceptr_t)d_out) == hipSuccess && sz) {
      size_t avail = sz - (size_t)((char*)d_out - (char*)base);
      size_t need_f32 = (size_t)out_size * 4;
      // positive evidence only: exactly-f32-sized dedicated allocation
      if (avail >= need_f32 && avail <= need_f32 + need_f32 / 2) out_f32 = 1;
    }
  }

  // ---- compact workspace layout (~41 MB) ----------------------------------
  char* ws = (char*)d_ws;
  size_t off = 0;
  auto alloc = [&](size_t bytes) {
    void* p = ws + off;
    off += (bytes + 255) & ~(size_t)255;
    return p;
  };
  int*   flag = (int*)  alloc(256);
  u16*   x    = (u16*)  alloc((size_t)NTOK * E_DIM * 2);  // conv scratch, reused as ctx
  u16*   qp   = (u16*)  alloc((size_t)NTOK * E_DIM * 2);
  u16*   kp   = (u16*)  alloc((size_t)NTOK * E_DIM * 2);
  u16*   vp   = (u16*)  alloc((size_t)NTOK * E_DIM * 2);
  u16*   wq   = (u16*)  alloc((size_t)E_DIM * E_DIM * 2);
  u16*   wk   = (u16*)  alloc((size_t)E_DIM * E_DIM * 2);
  u16*   wv   = (u16*)  alloc((size_t)E_DIM * E_DIM * 2);
  u16*   wo   = (u16*)  alloc((size_t)E_DIM * E_DIM * 2);
  float* bqf  = (float*)alloc(E_DIM * 4);
  float* bkf  = (float*)alloc(E_DIM * 4);
  float* bvf  = (float*)alloc(E_DIM * 4);
  float* bof  = (float*)alloc(E_DIM * 4);
  if (off > ws_size) return;  // ws too small: clean zero output as diagnostic

  detect_dtype<<<1, 64, 0, stream>>>((const u16*)query, flag);

  to_bf16<<<256, 256, 0, stream>>>(Wq, wq, E_DIM * E_DIM, flag);
  to_bf16<<<256, 256, 0, stream>>>(Wk, wk, E_DIM * E_DIM, flag);
  to_bf16<<<256, 256, 0, stream>>>(Wv, wv, E_DIM * E_DIM, flag);
  to_bf16<<<256, 256, 0, stream>>>(Wo, wo, E_DIM * E_DIM, flag);
  to_f32<<<4, 256, 0, stream>>>(bq, bqf, E_DIM, flag);
  to_f32<<<4, 256, 0, stream>>>(bk, bkf, E_DIM, flag);
  to_f32<<<4, 256, 0, stream>>>(bv, bvf, E_DIM, flag);
  to_f32<<<4, 256, 0, stream>>>(bo, bof, E_DIM, flag);

  dim3 gg(E_DIM / 64, NTOK / 64);
  // q projection
  to_bf16<<<1024, 256, 0, stream>>>(query, x, NTOK * E_DIM, flag);
  gemm_nt<<<gg, 256, 0, stream>>>(x, wq, bqf, qp, NTOK, E_DIM, E_DIM, 0.125f, 0);
  // k projection
  to_bf16<<<1024, 256, 0, stream>>>(key, x, NTOK * E_DIM, flag);
  gemm_nt<<<gg, 256, 0, stream>>>(x, wk, bkf, kp, NTOK, E_DIM, E_DIM, 1.0f, 0);
  // v projection
  to_bf16<<<1024, 256, 0, stream>>>(value, x, NTOK * E_DIM, flag);
  gemm_nt<<<gg, 256, 0, stream>>>(x, wv, bvf, vp, NTOK, E_DIM, E_DIM, 1.0f, 0);

  // attention (ctx written into x scratch — free after v projection)
  u16* ctx = x;
  flash_attn<<<dim3(T_DIM / 64, B_DIM * H_DIM), 256, 0, stream>>>(
      qp, kp, vp, amask, kpm, ctx, flag);

  // output projection, dtype per host decision
  gemm_nt<<<gg, 256, 0, stream>>>(ctx, wo, bof, d_out, NTOK, E_DIM, E_DIM, 1.0f, out_f32);
}

// Round 3
// 485.232 us; speedup vs baseline: 1.0348x; 1.0348x over previous
//
#include <hip/hip_runtime.h>
#include <hip/hip_bf16.h>

typedef unsigned short u16;
typedef __attribute__((ext_vector_type(8))) short bf16x8;
typedef __attribute__((ext_vector_type(4))) float f32x4;

#define T_DIM 2048
#define S_DIM 2048
#define B_DIM 2
#define E_DIM 1024
#define H_DIM 16
#define D_HEAD 64
#define NTOK 4096  // T*B

__device__ __forceinline__ float bf2f(u16 u) {
  union { unsigned int i; float f; } v; v.i = ((unsigned int)u) << 16; return v.f;
}
__device__ __forceinline__ u16 f2bf(float f) {
  union { float f; unsigned int i; } v; v.f = f;
  unsigned int r = v.i + 0x7fffu + ((v.i >> 16) & 1u);
  return (u16)(r >> 16);
}

// ---- dtype detector: flag=1 if input buffers are bf16, 0 if f32 -------------
__global__ void detect_dtype(const u16* q, int* flag) {
  int lane = threadIdx.x;  // 64 threads
  float v = bf2f(q[2 * lane]);
  bool ok = (v < 16.f) && (v > -16.f);
  unsigned long long b = __ballot(ok);
  if (lane == 0) *flag = (b == ~0ull) ? 1 : 0;
}

__global__ void to_bf16(const void* src, u16* dst, int n, const int* flag) {
  int i = blockIdx.x * blockDim.x + threadIdx.x;
  int stride = gridDim.x * blockDim.x;
  if (*flag) {
    const u16* s = (const u16*)src;
    for (; i < n; i += stride) dst[i] = s[i];
  } else {
    const float* s = (const float*)src;
    for (; i < n; i += stride) dst[i] = f2bf(s[i]);
  }
}

__global__ void to_f32(const void* src, float* dst, int n, const int* flag) {
  int i = blockIdx.x * blockDim.x + threadIdx.x;
  int stride = gridDim.x * blockDim.x;
  if (*flag) {
    const u16* s = (const u16*)src;
    for (; i < n; i += stride) dst[i] = bf2f(s[i]);
  } else {
    const float* s = (const float*)src;
    for (; i < n; i += stride) dst[i] = s[i];
  }
}

// ---- per-head V transpose: vt[(b*16+h)*64+d][s] = vp[s,b,h*64+d] ------------
// Conflict-free: u16 values in dword LDS slots, pitch 65 (odd) -> 2-way max.
__launch_bounds__(256)
__global__ void transpose_v(const u16* __restrict__ vp, u16* __restrict__ vt) {
  __shared__ unsigned int t[64 * 65];
  const int tid = threadIdx.x;
  const int s0 = blockIdx.x * 64;
  const int bh = blockIdx.y;
  const int b = bh / H_DIM, h = bh % H_DIM;
  {
    int sr = tid >> 2, cq = (tid & 3) * 16;
    const u16* src = &vp[((size_t)(s0 + sr) * B_DIM + b) * E_DIM + h * 64 + cq];
    u16 v[16];
    *(uint4*)&v[0] = *(const uint4*)&src[0];
    *(uint4*)&v[8] = *(const uint4*)&src[8];
#pragma unroll
    for (int j = 0; j < 16; j++) t[(cq + j) * 65 + sr] = v[j];
  }
  __syncthreads();
  {
    int d = tid >> 2, sq = (tid & 3) * 16;
    u16 o[16];
#pragma unroll
    for (int j = 0; j < 16; j++) o[j] = (u16)t[d * 65 + sq + j];
    u16* dst = &vt[((size_t)bh * 64 + d) * S_DIM + s0 + sq];
    *(uint4*)&dst[0] = *(uint4*)&o[0];
    *(uint4*)&dst[8] = *(uint4*)&o[8];
  }
}

// ---- NT GEMM 128x128 tile (m93 shape): 4 waves, each 64x64 = 4x4 MFMA tiles -
__launch_bounds__(256)
__global__ void gemm_nt128(const u16* __restrict__ A, const u16* __restrict__ Bw,
                           const float* __restrict__ bias, void* __restrict__ C,
                           int M, int N, int K, float scale, int out_f32) {
  __shared__ alignas(16) u16 As[128 * 72];
  __shared__ alignas(16) u16 Bs[128 * 72];
  const int tid = threadIdx.x;
  const int wave = tid >> 6, lane = tid & 63;
  const int g = lane >> 4, c = lane & 15;
  const int wy = wave >> 1, wx = wave & 1;
  const int m0 = blockIdx.y * 128, n0 = blockIdx.x * 128;
  f32x4 acc[4][4] = {};
  for (int kc = 0; kc < K; kc += 64) {
#pragma unroll
    for (int i = 0; i < 4; i++) {
      int ch = tid + i * 256;  // 1024 chunks of 16B per tile
      int r = ch >> 3, o = (ch & 7) * 8;
      *(uint4*)&As[r * 72 + o] = *(const uint4*)&A[(size_t)(m0 + r) * K + kc + o];
      *(uint4*)&Bs[r * 72 + o] = *(const uint4*)&Bw[(size_t)(n0 + r) * K + kc + o];
    }
    __syncthreads();
#pragma unroll
    for (int ks = 0; ks < 2; ks++) {
      bf16x8 av[4], bv[4];
#pragma unroll
      for (int mi = 0; mi < 4; mi++)
        av[mi] = *(const bf16x8*)&As[(wy * 64 + mi * 16 + c) * 72 + ks * 32 + g * 8];
#pragma unroll
      for (int ni = 0; ni < 4; ni++)
        bv[ni] = *(const bf16x8*)&Bs[(wx * 64 + ni * 16 + c) * 72 + ks * 32 + g * 8];
#pragma unroll
      for (int mi = 0; mi < 4; mi++)
#pragma unroll
        for (int ni = 0; ni < 4; ni++)
          acc[mi][ni] = __builtin_amdgcn_mfma_f32_16x16x32_bf16(av[mi], bv[ni], acc[mi][ni], 0, 0, 0);
    }
    __syncthreads();
  }
#pragma unroll
  for (int mi = 0; mi < 4; mi++)
#pragma unroll
    for (int ni = 0; ni < 4; ni++)
#pragma unroll
      for (int r = 0; r < 4; r++) {
        int row = m0 + wy * 64 + mi * 16 + g * 4 + r;
        int col = n0 + wx * 64 + ni * 16 + c;
        float v = (acc[mi][ni][r] + bias[col]) * scale;
        size_t idx = (size_t)row * N + col;
        if (out_f32) ((float*)C)[idx] = v;
        else         ((u16*)C)[idx] = f2bf(v);
      }
}

// ---- flash attention v2: Q in regs, V pre-transposed, mask via LDS ----------
__launch_bounds__(256)
__global__ void flash_attn(const u16* __restrict__ Qb, const u16* __restrict__ Kb,
                           const u16* __restrict__ Vtg, const void* __restrict__ mask,
                           const unsigned char* __restrict__ kpm,
                           u16* __restrict__ ctx, const int* __restrict__ flag) {
  __shared__ alignas(16) u16 Ks[64 * 72];
  __shared__ alignas(16) u16 Vs[64 * 72];   // Vs[d][s]
  __shared__ alignas(16) u16 MP[64 * 72];   // mask tile, then P (wave-private rows)
  const int tid = threadIdx.x;
  const int wave = tid >> 6, lane = tid & 63;
  const int g = lane >> 4, c = lane & 15;
  const int bh = blockIdx.x;                // bh fastest: co-dispatched blocks share mask rows
  const int t0 = blockIdx.y * 64;
  const int b = bh / H_DIM, h = bh % H_DIM;
  const size_t hoff = (size_t)h * D_HEAD;
  const int mask_bf = *flag;
  const float L2E = 1.44269504f;

  // stage Q through Ks, hoist fragments to registers
#pragma unroll
  for (int i = 0; i < 2; i++) {
    int ch = tid + i * 256;
    int r = ch >> 3, o = (ch & 7) * 8;
    *(uint4*)&Ks[r * 72 + o] =
        *(const uint4*)&Qb[((size_t)(t0 + r) * B_DIM + b) * E_DIM + hoff + o];
  }
  __syncthreads();
  const int arow = wave * 16 + c;
  bf16x8 q0 = *(const bf16x8*)&Ks[arow * 72 + g * 8];
  bf16x8 q1 = *(const bf16x8*)&Ks[arow * 72 + 32 + g * 8];
  __syncthreads();

  f32x4 O[4] = {};
  float mrow[4] = {-1e30f, -1e30f, -1e30f, -1e30f};
  float lrow[4] = {0.f, 0.f, 0.f, 0.f};

  for (int s0 = 0; s0 < S_DIM; s0 += 64) {
    // stage K rows(s), V^T rows(d), mask rows(t) — all coalesced uint4
#pragma unroll
    for (int i = 0; i < 2; i++) {
      int ch = tid + i * 256;
      int r = ch >> 3, o = (ch & 7) * 8;
      *(uint4*)&Ks[r * 72 + o] =
          *(const uint4*)&Kb[((size_t)(s0 + r) * B_DIM + b) * E_DIM + hoff + o];
      *(uint4*)&Vs[r * 72 + o] =
          *(const uint4*)&Vtg[((size_t)bh * 64 + r) * S_DIM + s0 + o];
      if (mask_bf) {
        *(uint4*)&MP[r * 72 + o] =
            *(const uint4*)&((const u16*)mask)[(size_t)(t0 + r) * S_DIM + s0 + o];
      } else {
        const float* mf = (const float*)mask + (size_t)(t0 + r) * S_DIM + s0 + o;
#pragma unroll
        for (int j = 0; j < 8; j++) MP[r * 72 + o + j] = f2bf(mf[j]);
      }
    }
    __syncthreads();

    // QK^T
    f32x4 sc[4] = {};
#pragma unroll
    for (int n = 0; n < 4; n++) {
      bf16x8 k0 = *(const bf16x8*)&Ks[(n * 16 + c) * 72 + g * 8];
      bf16x8 k1 = *(const bf16x8*)&Ks[(n * 16 + c) * 72 + 32 + g * 8];
      sc[n] = __builtin_amdgcn_mfma_f32_16x16x32_bf16(q0, k0, sc[n], 0, 0, 0);
      sc[n] = __builtin_amdgcn_mfma_f32_16x16x32_bf16(q1, k1, sc[n], 0, 0, 0);
    }
    // masks (read BEFORE overwriting MP with P; rows are wave-private)
    float kadd[4];
#pragma unroll
    for (int n = 0; n < 4; n++) {
      int s = s0 + n * 16 + c;
      kadd[n] = kpm[(size_t)b * S_DIM + s] ? -1e9f : 0.f;
    }
#pragma unroll
    for (int n = 0; n < 4; n++)
#pragma unroll
      for (int r = 0; r < 4; r++) {
        float mv = bf2f(MP[(wave * 16 + g * 4 + r) * 72 + n * 16 + c]);
        sc[n][r] = (sc[n][r] + mv + kadd[n]) * L2E;  // log2 domain
      }
    // online softmax
    float al[4];
#pragma unroll
    for (int r = 0; r < 4; r++) {
      float mx = fmaxf(fmaxf(sc[0][r], sc[1][r]), fmaxf(sc[2][r], sc[3][r]));
#pragma unroll
      for (int off = 1; off < 16; off <<= 1) mx = fmaxf(mx, __shfl_xor(mx, off, 64));
      float mn = fmaxf(mrow[r], mx);
      al[r] = exp2f(mrow[r] - mn);
      mrow[r] = mn;
    }
    float rs[4] = {0.f, 0.f, 0.f, 0.f};
#pragma unroll
    for (int n = 0; n < 4; n++)
#pragma unroll
      for (int r = 0; r < 4; r++) {
        float pv = exp2f(sc[n][r] - mrow[r]);
        rs[r] += pv;
        MP[(wave * 16 + g * 4 + r) * 72 + n * 16 + c] = f2bf(pv);
      }
#pragma unroll
    for (int r = 0; r < 4; r++) {
      float s = rs[r];
#pragma unroll
      for (int off = 1; off < 16; off <<= 1) s += __shfl_xor(s, off, 64);
      lrow[r] = lrow[r] * al[r] + s;
      O[0][r] *= al[r]; O[1][r] *= al[r]; O[2][r] *= al[r]; O[3][r] *= al[r];
    }
    // PV
    bf16x8 p0 = *(const bf16x8*)&MP[arow * 72 + g * 8];
    bf16x8 p1 = *(const bf16x8*)&MP[arow * 72 + 32 + g * 8];
#pragma unroll
    for (int n = 0; n < 4; n++) {
      bf16x8 v0 = *(const bf16x8*)&Vs[(n * 16 + c) * 72 + g * 8];
      bf16x8 v1 = *(const bf16x8*)&Vs[(n * 16 + c) * 72 + 32 + g * 8];
      O[n] = __builtin_amdgcn_mfma_f32_16x16x32_bf16(p0, v0, O[n], 0, 0, 0);
      O[n] = __builtin_amdgcn_mfma_f32_16x16x32_bf16(p1, v1, O[n], 0, 0, 0);
    }
    __syncthreads();
  }
#pragma unroll
  for (int n = 0; n < 4; n++)
#pragma unroll
    for (int r = 0; r < 4; r++) {
      int t = t0 + wave * 16 + g * 4 + r;
      int dcol = n * 16 + c;
      float v = O[n][r] / lrow[r];
      ctx[((size_t)t * B_DIM + b) * E_DIM + hoff + dcol] = f2bf(v);
    }
}

extern "C" void kernel_launch(void* const* d_in, const int* in_sizes, int n_in,
                              void* d_out, int out_size, void* d_ws, size_t ws_size,
                              hipStream_t stream) {
  const void* query = d_in[0];
  const void* key   = d_in[1];
  const void* value = d_in[2];
  const void* amask = d_in[3];
  const unsigned char* kpm = (const unsigned char*)d_in[4];
  const void* Wq = d_in[5];  const void* bq = d_in[6];
  const void* Wk = d_in[7];  const void* bk = d_in[8];
  const void* Wv = d_in[9];  const void* bv = d_in[10];
  const void* Wo = d_in[11]; const void* bo = d_in[12];

  // output dtype decision (host, capture-safe) — unchanged from passing round
  int out_f32 = 0;
  {
    hipDeviceptr_t base = nullptr; size_t sz = 0;
    if (hipMemGetAddressRange(&base, &sz, (hipDeviceptr_t)d_out) == hipSuccess && sz) {
      size_t avail = sz - (size_t)((char*)d_out - (char*)base);
      size_t need_f32 = (size_t)out_size * 4;
      if (avail >= need_f32 && avail <= need_f32 + need_f32 / 2) out_f32 = 1;
    }
  }

  char* ws = (char*)d_ws;
  size_t off = 0;
  auto alloc = [&](size_t bytes) {
    void* p = ws + off;
    off += (bytes + 255) & ~(size_t)255;
    return p;
  };
  int*   flag = (int*)  alloc(256);
  u16*   x    = (u16*)  alloc((size_t)NTOK * E_DIM * 2);  // conv scratch -> ctx
  u16*   qp   = (u16*)  alloc((size_t)NTOK * E_DIM * 2);
  u16*   kp   = (u16*)  alloc((size_t)NTOK * E_DIM * 2);
  u16*   vp   = (u16*)  alloc((size_t)NTOK * E_DIM * 2);
  u16*   vt   = (u16*)  alloc((size_t)NTOK * E_DIM * 2);  // per-head transposed V
  u16*   wq   = (u16*)  alloc((size_t)E_DIM * E_DIM * 2);
  u16*   wk   = (u16*)  alloc((size_t)E_DIM * E_DIM * 2);
  u16*   wv   = (u16*)  alloc((size_t)E_DIM * E_DIM * 2);
  u16*   wo   = (u16*)  alloc((size_t)E_DIM * E_DIM * 2);
  float* bqf  = (float*)alloc(E_DIM * 4);
  float* bkf  = (float*)alloc(E_DIM * 4);
  float* bvf  = (float*)alloc(E_DIM * 4);
  float* bof  = (float*)alloc(E_DIM * 4);
  if (off > ws_size) return;

  detect_dtype<<<1, 64, 0, stream>>>((const u16*)query, flag);

  to_bf16<<<256, 256, 0, stream>>>(Wq, wq, E_DIM * E_DIM, flag);
  to_bf16<<<256, 256, 0, stream>>>(Wk, wk, E_DIM * E_DIM, flag);
  to_bf16<<<256, 256, 0, stream>>>(Wv, wv, E_DIM * E_DIM, flag);
  to_bf16<<<256, 256, 0, stream>>>(Wo, wo, E_DIM * E_DIM, flag);
  to_f32<<<4, 256, 0, stream>>>(bq, bqf, E_DIM, flag);
  to_f32<<<4, 256, 0, stream>>>(bk, bkf, E_DIM, flag);
  to_f32<<<4, 256, 0, stream>>>(bv, bvf, E_DIM, flag);
  to_f32<<<4, 256, 0, stream>>>(bo, bof, E_DIM, flag);

  dim3 gg(E_DIM / 128, NTOK / 128);
  to_bf16<<<1024, 256, 0, stream>>>(query, x, NTOK * E_DIM, flag);
  gemm_nt128<<<gg, 256, 0, stream>>>(x, wq, bqf, qp, NTOK, E_DIM, E_DIM, 0.125f, 0);
  to_bf16<<<1024, 256, 0, stream>>>(key, x, NTOK * E_DIM, flag);
  gemm_nt128<<<gg, 256, 0, stream>>>(x, wk, bkf, kp, NTOK, E_DIM, E_DIM, 1.0f, 0);
  to_bf16<<<1024, 256, 0, stream>>>(value, x, NTOK * E_DIM, flag);
  gemm_nt128<<<gg, 256, 0, stream>>>(x, wv, bvf, vp, NTOK, E_DIM, E_DIM, 1.0f, 0);

  transpose_v<<<dim3(S_DIM / 64, B_DIM * H_DIM), 256, 0, stream>>>(vp, vt);

  u16* ctx = x;  // free after v projection
  flash_attn<<<dim3(B_DIM * H_DIM, T_DIM / 64), 256, 0, stream>>>(
      qp, kp, vt, amask, kpm, ctx, flag);

  gemm_nt128<<<gg, 256, 0, stream>>>(ctx, wo, bof, d_out, NTOK, E_DIM, E_DIM, 1.0f, out_f32);
}